// Round 9
// baseline (158.728 us; speedup 1.0000x reference)
//
#include <hip/hip_runtime.h>

// Problem constants (from reference)
#define M_PTS   16385     // int(65536*0.25)+1
#define K_NB    16
#define CIN_C   256
#define COUT_C  512
#define N_ROWS  65536
#define LN_EPS  1e-5f

#define OUT_XYZ_ELEMS (M_PTS * 3)                      // 49155
#define OUT_FEAT_OFF  OUT_XYZ_ELEMS
#define OUT_NOFF_IDX  (OUT_XYZ_ELEMS + M_PTS * COUT_C) // 8438275

// prep grid: 2048 grid-strided LN blocks (2 rows/wave/iter x 4 iters)
//          + 512 blocks weight/xyz prep
#define LN_BLOCKS   2048
#define PREP_BLOCKS 512

// main grid: 513 blocks x 32 points (R6-verified config)
#define NBLK 513
#define PPB  32

#define B_SCALE 16.0f     // lin_w pre-scale (keeps e4m3 out of subnormals)
#define B_INV   0.0625f

#define AROW_B 272        // A-tile row stride in LDS BYTES (256 fp8 + 16 pad)

typedef __attribute__((ext_vector_type(4))) float f32x4;
typedef __attribute__((ext_vector_type(2))) unsigned int uint2v;

// Full-wave (64-lane) float sum on the VALU pipe via DPP — no DS-pipe ops.
__device__ __forceinline__ float wave_sum64(float v) {
  v += __int_as_float(__builtin_amdgcn_update_dpp(0, __float_as_int(v), 0xB1, 0xF, 0xF, false));
  v += __int_as_float(__builtin_amdgcn_update_dpp(0, __float_as_int(v), 0x4E, 0xF, 0xF, false));
  v += __int_as_float(__builtin_amdgcn_update_dpp(0, __float_as_int(v), 0x141, 0xF, 0xF, false));
  v += __int_as_float(__builtin_amdgcn_update_dpp(0, __float_as_int(v), 0x140, 0xF, 0xF, false));
  v += __int_as_float(__builtin_amdgcn_update_dpp(0, __float_as_int(v), 0x142, 0xA, 0xF, false));
  v += __int_as_float(__builtin_amdgcn_update_dpp(0, __float_as_int(v), 0x143, 0xC, 0xF, false));
  return __int_as_float(__builtin_amdgcn_readlane(__float_as_int(v), 63));
}

// LayerNorm the wave's 256-ch row (lane holds ch 4L..4L+3) and pack to 4 fp8.
// Bit-identical math to the verified R1/R6 version (absmax 0.203125).
__device__ __forceinline__ int ln_pack(float4 g, float4 nw, float4 nb) {
  float s1 = (g.x + g.y) + (g.z + g.w);
  float s2 = g.x * g.x + g.y * g.y + g.z * g.z + g.w * g.w;
  float S1 = wave_sum64(s1);
  float S2 = wave_sum64(s2);
  float mu  = S1 * (1.0f / 256.0f);
  float var = fmaf(-mu, mu, S2 * (1.0f / 256.0f));
  float rs  = rsqrtf(var + LN_EPS);
  float a = fmaf((g.x - mu) * rs, nw.x, nb.x);
  float b = fmaf((g.y - mu) * rs, nw.y, nb.y);
  float c = fmaf((g.z - mu) * rs, nw.z, nb.z);
  float d = fmaf((g.w - mu) * rs, nw.w, nb.w);
  int v = __builtin_amdgcn_cvt_pk_fp8_f32(a, b, 0, false);   // bytes 0,1
  v = __builtin_amdgcn_cvt_pk_fp8_f32(c, d, v, true);        // bytes 2,3
  return v;
}

// R1-verified table-row byte layout (16x16x32 A-frag order): the dword holding
// channels 4L..4L+3 lands so the MFMA (kk=2t, kk=2t+1) frag pair is contiguous
// 16 B at t*64 + quad*16.
__device__ __forceinline__ int wdw_of(int lane) {
  return ((lane >> 4) << 6) + (((lane >> 1) & 3) << 4)
       + (lane & 8) + ((lane & 1) << 2);
}

// Prep (R8-verified):
//  blocks [0, 2048): LayerNorm + fp8-pack ALL 65536 feats rows into the 16 MB
//    table — grid-strided, TWO rows per wave per iteration (4 interleavable
//    DPP chains hide the dependent-reduce latency).
//  blocks [2048, 2560): lin_w -> fp8 x16 swizzle, n_xyz gather, n_offset.
__global__ void prep_kernel(const float* __restrict__ lin_w,
                            const float* __restrict__ xyz,
                            const float* __restrict__ feats,
                            const float* __restrict__ norm_w,
                            const float* __restrict__ norm_b,
                            const int*   __restrict__ samp_idx,
                            const int*   __restrict__ offset,
                            unsigned char* __restrict__ lw8,
                            unsigned char* __restrict__ tab,
                            float*  __restrict__ out) {
  int bx = blockIdx.x;
  if (bx < LN_BLOCKS) {
    const int lane = threadIdx.x & 63;
    const int gw   = (bx << 2) + (threadIdx.x >> 6);  // global wave 0..8191
    const float4 nw = ((const float4*)norm_w)[lane];
    const float4 nb = ((const float4*)norm_b)[lane];
    const float4* f4 = (const float4*)feats;
    const int wo = wdw_of(lane);
#pragma unroll
    for (int i = 0; i < 4; ++i) {
      const int ra = (i << 14) + (gw << 1);           // rows ra, ra+1
      float4 ga = f4[(size_t)ra * 64 + lane];
      float4 gb = f4[(size_t)(ra + 1) * 64 + lane];
      int pka = ln_pack(ga, nw, nb);                  // independent chains —
      int pkb = ln_pack(gb, nw, nb);                  // scheduler interleaves
      *(int*)(tab + ((size_t)ra << 8) + wo)       = pka;
      *(int*)(tab + ((size_t)(ra + 1) << 8) + wo) = pkb;
    }
    return;
  }
  int tid = (bx - LN_BLOCKS) * 256 + threadIdx.x;
  if (tid < COUT_C * CIN_C) {
    int o = tid >> 8;          // 0..511  (cout)
    int c = tid & 255;         // 0..255  (cin)
    // R1-verified 32-col wave B layout: Breg[kk][g] at lane (quad*16+lcol),
    // byte e = fp8(16 * lin_w[o = w*32 + g*16 + lcol][c = kk*32 + quad*8 + e])
    // pos = w*8192 + g*4096 + kk*512 + (quad*16+lcol)*8 + e
    int pos = ((o >> 5) << 13) | (((o >> 4) & 1) << 12) | ((c >> 5) << 9)
            | ((((c >> 3) & 3) * 16 + (o & 15)) << 3) | (c & 7);
    int pk = __builtin_amdgcn_cvt_pk_fp8_f32(lin_w[tid] * B_SCALE, 0.0f, 0, false);
    lw8[pos] = (unsigned char)(pk & 0xFF);
  }
  if (tid < OUT_XYZ_ELEMS) {
    int p = tid / 3;
    int c = tid - p * 3;
    out[tid] = xyz[(size_t)samp_idx[p] * 3 + c];
  }
  if (tid == 0) out[OUT_NOFF_IDX] = (float)(offset[0] / 4 + 1);
}

// One 256 B table row -> LDS via direct DMA (4 B/lane, wave-uniform LDS base).
// src = tabL + preshifted row byte offset (Kidx holds idx<<8).
__device__ __forceinline__ void load_row(const unsigned char* __restrict__ src,
                                         unsigned char* ldsrow) {
  __builtin_amdgcn_global_load_lds(
      (const __attribute__((address_space(1))) unsigned int*)src,
      (__attribute__((address_space(3))) unsigned int*)ldsrow,
      4, 0, 0);
}

// 16-row maxpool reduce on the VALU pipe via permlane-swap BUILTINS (no DS
// ops, no inline asm). Robust to the swap's row-assignment convention: with
// both inputs equal to v, the two outputs partition {v[l], v[l^16]} per lane,
// so max(out0,out1)[l] = max(v[l], v[l^16]); same at ^32. fmax tree order is
// identical to the shfl_xor version -> bitwise-identical results.
__device__ __forceinline__ float pool16(f32x4 a) {
  float v = fmaxf(fmaxf(a[0], a[1]), fmaxf(a[2], a[3]));
  uint2v r = __builtin_amdgcn_permlane16_swap(__float_as_uint(v), __float_as_uint(v), false, false);
  v = fmaxf(__uint_as_float(r.x), __uint_as_float(r.y));
  uint2v s = __builtin_amdgcn_permlane32_swap(__float_as_uint(v), __float_as_uint(v), false, false);
  return fmaxf(__uint_as_float(s.x), __uint_as_float(s.y));
}

// GEMM one point's 16x256 fp8 A-tile against the wave's 32-col B registers,
// then maxpool over the 16 rows. MFMA chain and LDS reads EXACTLY R6/R8;
// only the cross-lane maxpool moved from DS-pipe shfl_xor to VALU permlane.
__device__ __forceinline__ void gemm_pool(const unsigned char* rowbase,
                                          const long Breg[8][2], int quad,
                                          float& v0, float& v1) {
  ulonglong2 q0 = *(const ulonglong2*)(rowbase + 0   + quad * 16);
  ulonglong2 q1 = *(const ulonglong2*)(rowbase + 64  + quad * 16);
  ulonglong2 q2 = *(const ulonglong2*)(rowbase + 128 + quad * 16);
  ulonglong2 q3 = *(const ulonglong2*)(rowbase + 192 + quad * 16);
  f32x4 a0 = {0.f, 0.f, 0.f, 0.f}, a1 = {0.f, 0.f, 0.f, 0.f};
  a0 = __builtin_amdgcn_mfma_f32_16x16x32_fp8_fp8((long)q0.x, Breg[0][0], a0, 0, 0, 0);
  a1 = __builtin_amdgcn_mfma_f32_16x16x32_fp8_fp8((long)q0.x, Breg[0][1], a1, 0, 0, 0);
  a0 = __builtin_amdgcn_mfma_f32_16x16x32_fp8_fp8((long)q0.y, Breg[1][0], a0, 0, 0, 0);
  a1 = __builtin_amdgcn_mfma_f32_16x16x32_fp8_fp8((long)q0.y, Breg[1][1], a1, 0, 0, 0);
  a0 = __builtin_amdgcn_mfma_f32_16x16x32_fp8_fp8((long)q1.x, Breg[2][0], a0, 0, 0, 0);
  a1 = __builtin_amdgcn_mfma_f32_16x16x32_fp8_fp8((long)q1.x, Breg[2][1], a1, 0, 0, 0);
  a0 = __builtin_amdgcn_mfma_f32_16x16x32_fp8_fp8((long)q1.y, Breg[3][0], a0, 0, 0, 0);
  a1 = __builtin_amdgcn_mfma_f32_16x16x32_fp8_fp8((long)q1.y, Breg[3][1], a1, 0, 0, 0);
  a0 = __builtin_amdgcn_mfma_f32_16x16x32_fp8_fp8((long)q2.x, Breg[4][0], a0, 0, 0, 0);
  a1 = __builtin_amdgcn_mfma_f32_16x16x32_fp8_fp8((long)q2.x, Breg[4][1], a1, 0, 0, 0);
  a0 = __builtin_amdgcn_mfma_f32_16x16x32_fp8_fp8((long)q2.y, Breg[5][0], a0, 0, 0, 0);
  a1 = __builtin_amdgcn_mfma_f32_16x16x32_fp8_fp8((long)q2.y, Breg[5][1], a1, 0, 0, 0);
  a0 = __builtin_amdgcn_mfma_f32_16x16x32_fp8_fp8((long)q3.x, Breg[6][0], a0, 0, 0, 0);
  a1 = __builtin_amdgcn_mfma_f32_16x16x32_fp8_fp8((long)q3.x, Breg[6][1], a1, 0, 0, 0);
  a0 = __builtin_amdgcn_mfma_f32_16x16x32_fp8_fp8((long)q3.y, Breg[7][0], a0, 0, 0, 0);
  a1 = __builtin_amdgcn_mfma_f32_16x16x32_fp8_fp8((long)q3.y, Breg[7][1], a1, 0, 0, 0);
  // D layout: col = lane&15, row = quad*4 + reg (validated). Maxpool 16 rows.
  v0 = pool16(a0);
  v1 = pool16(a1);
}

// Fused main — R6/R8 structure (measured 52.6-53.1 us, absmax 0.203125):
// 1024 threads = 16 waves, 2 points/iter, 4-deep LDS rotation, counted-vmcnt
// 3/2/1, one raw barrier per iteration, runtime min() tail, NBLK=513.
__global__ __launch_bounds__(1024, 8)
void td_main(const unsigned char* __restrict__ tab,
             const unsigned char* __restrict__ lw8,
             const int*    __restrict__ knn,
             float* __restrict__ out) {
  __shared__ __align__(16) unsigned char A8[4][32][AROW_B]; // 34816 B
  __shared__ int Kidx[PPB * K_NB];                          // 2048 B

  const int tid  = threadIdx.x;
  const int lane = tid & 63;
  const int w    = tid >> 6;        // wave = neighbor row AND 32-col chunk
  const int quad = lane >> 4;
  const int lcol = lane & 15;

  const int pstart = blockIdx.x * PPB;
  const int npts   = min(pstart + PPB, M_PTS) - pstart;
  if (npts <= 0) return;

  // Stage this block's knn indices, PRE-SHIFTED to row byte offsets (idx*256)
  for (int i = tid; i < npts * K_NB; i += 1024)
    Kidx[i] = knn[pstart * K_NB + i] << 8;

  // Persistent fp8 B chunk: Breg[kk][g], 32 VGPRs, coalesced 8B/lane loads
  long Breg[8][2];
  {
    const unsigned char* base = lw8 + (w << 13) + lane * 8;
#pragma unroll
    for (int g = 0; g < 2; ++g)
#pragma unroll
      for (int kk = 0; kk < 8; ++kk) {
        Breg[kk][g] = *(const long*)(base + (g << 12) + (kk << 9));
        asm volatile("" : "+v"(Breg[kk][g]));   // opaque: cannot be re-sunk
      }
  }

  const unsigned char* tabL = tab + (lane << 2);  // hoisted per-lane base

  __syncthreads();                  // Kidx visible (full sync, once)

  // Preload pair 0 into buffer 0
  load_row(tabL + (unsigned)Kidx[w],                           &A8[0][w][0]);
  load_row(tabL + (unsigned)Kidx[min(1, npts - 1) * K_NB + w], &A8[0][16 + w][0]);

  const int nit = (npts + 1) >> 1;
  for (int it = 0; it < nit; ++it) {
    const int pa = 2 * it, pb = 2 * it + 1;

    // Prefetch pair it+1 into buffer (it+1)&3 (crosses the barrier un-drained)
    if (it + 1 < nit) {
      int qa = min(pa + 2, npts - 1), qb = min(pa + 3, npts - 1);
      int b = (it + 1) & 3;
      load_row(tabL + (unsigned)Kidx[qa * K_NB + w], &A8[b][w][0]);
      load_row(tabL + (unsigned)Kidx[qb * K_NB + w], &A8[b][16 + w][0]);
    }

    // Counted vmcnt — EXACT R6 pacing (steady 3, first 2, last 1).
    if (it == 0) {
      if (nit > 1) asm volatile("s_waitcnt vmcnt(2)" ::: "memory");
      else         asm volatile("s_waitcnt vmcnt(0)" ::: "memory");
    } else if (it + 1 < nit) {
      asm volatile("s_waitcnt vmcnt(3)" ::: "memory");
    } else {
      asm volatile("s_waitcnt vmcnt(1)" ::: "memory");
    }
    __builtin_amdgcn_s_barrier();   // all 32 rows of buffer it&3 landed

    const unsigned char* Ab = &A8[it & 3][0][0];

    // GEMM + maxpool, point a then point b (R6-exact stores)
    float v0, v1;
    gemm_pool(Ab + lcol * AROW_B, Breg, quad, v0, v1);
    float* outa = out + OUT_FEAT_OFF + (size_t)(pstart + pa) * COUT_C + w * 32;
    if (quad < 2) outa[quad * 16 + lcol] = (quad ? v1 : v0) * B_INV;

    gemm_pool(Ab + (16 + lcol) * AROW_B, Breg, quad, v0, v1);
    if (pb < npts) {
      float* outb = out + OUT_FEAT_OFF + (size_t)(pstart + pb) * COUT_C + w * 32;
      if (quad < 2) outb[quad * 16 + lcol] = (quad ? v1 : v0) * B_INV;
    }
    // A[it&1..] reuse at it+4 is ordered by the intervening barriers.
  }
}

extern "C" void kernel_launch(void* const* d_in, const int* in_sizes, int n_in,
                              void* d_out, int out_size, void* d_ws, size_t ws_size,
                              hipStream_t stream) {
  const float* xyz      = (const float*)d_in[0];
  const float* feats    = (const float*)d_in[1];
  const float* norm_w   = (const float*)d_in[2];
  const float* norm_b   = (const float*)d_in[3];
  const float* lin_w    = (const float*)d_in[4];
  const int*   samp_idx = (const int*)d_in[5];
  const int*   knn      = (const int*)d_in[6];
  const int*   offset   = (const int*)d_in[7];
  float* out = (float*)d_out;
  unsigned char* lw8 = (unsigned char*)d_ws;               // 128 KB fp8 weights
  unsigned char* tab = (unsigned char*)d_ws + (1 << 17);   // 16 MB normed-fp8 feats

  prep_kernel<<<LN_BLOCKS + PREP_BLOCKS, 256, 0, stream>>>(
      lin_w, xyz, feats, norm_w, norm_b, samp_idx, offset, lw8, tab, out);

  td_main<<<NBLK, 1024, 0, stream>>>(tab, lw8, knn, out);
}

// Round 10
// 148.360 us; speedup vs baseline: 1.0699x; 1.0699x over previous
//
#include <hip/hip_runtime.h>

// Problem constants (from reference)
#define M_PTS   16385     // int(65536*0.25)+1
#define K_NB    16
#define CIN_C   256
#define COUT_C  512
#define N_ROWS  65536
#define LN_EPS  1e-5f

#define OUT_XYZ_ELEMS (M_PTS * 3)                      // 49155
#define OUT_FEAT_OFF  OUT_XYZ_ELEMS
#define OUT_NOFF_IDX  (OUT_XYZ_ELEMS + M_PTS * COUT_C) // 8438275

// prep grid: 2048 grid-strided LN blocks (2 rows/wave/iter x 4 iters)
//          + 512 blocks weight/xyz prep
#define LN_BLOCKS   2048
#define PREP_BLOCKS 512

// main grid: 513 blocks x 32 points (R6/R9-verified config)
#define NBLK 513
#define PPB  32

#define B_SCALE 16.0f     // lin_w pre-scale (keeps e4m3 out of subnormals)
#define B_INV   0.0625f
#define SCL_ONE 0x7F7F7F7F  // e8m0 127 = 2^0 in every byte -> identity scale

#define AROW_B 272        // A-tile row stride in LDS BYTES (256 fp8 + 16 pad)

typedef __attribute__((ext_vector_type(4))) float f32x4;
typedef __attribute__((ext_vector_type(8))) int   i32x8;
typedef __attribute__((ext_vector_type(2))) unsigned int uint2v;

// Full-wave (64-lane) float sum on the VALU pipe via DPP — no DS-pipe ops.
__device__ __forceinline__ float wave_sum64(float v) {
  v += __int_as_float(__builtin_amdgcn_update_dpp(0, __float_as_int(v), 0xB1, 0xF, 0xF, false));
  v += __int_as_float(__builtin_amdgcn_update_dpp(0, __float_as_int(v), 0x4E, 0xF, 0xF, false));
  v += __int_as_float(__builtin_amdgcn_update_dpp(0, __float_as_int(v), 0x141, 0xF, 0xF, false));
  v += __int_as_float(__builtin_amdgcn_update_dpp(0, __float_as_int(v), 0x140, 0xF, 0xF, false));
  v += __int_as_float(__builtin_amdgcn_update_dpp(0, __float_as_int(v), 0x142, 0xA, 0xF, false));
  v += __int_as_float(__builtin_amdgcn_update_dpp(0, __float_as_int(v), 0x143, 0xC, 0xF, false));
  return __int_as_float(__builtin_amdgcn_readlane(__float_as_int(v), 63));
}

// LayerNorm the wave's 256-ch row (lane holds ch 4L..4L+3) and pack to 4 fp8.
// Bit-identical math to the verified R1/R9 version.
__device__ __forceinline__ int ln_pack(float4 g, float4 nw, float4 nb) {
  float s1 = (g.x + g.y) + (g.z + g.w);
  float s2 = g.x * g.x + g.y * g.y + g.z * g.z + g.w * g.w;
  float S1 = wave_sum64(s1);
  float S2 = wave_sum64(s2);
  float mu  = S1 * (1.0f / 256.0f);
  float var = fmaf(-mu, mu, S2 * (1.0f / 256.0f));
  float rs  = rsqrtf(var + LN_EPS);
  float a = fmaf((g.x - mu) * rs, nw.x, nb.x);
  float b = fmaf((g.y - mu) * rs, nw.y, nb.y);
  float c = fmaf((g.z - mu) * rs, nw.z, nb.z);
  float d = fmaf((g.w - mu) * rs, nw.w, nb.w);
  int v = __builtin_amdgcn_cvt_pk_fp8_f32(a, b, 0, false);   // bytes 0,1
  v = __builtin_amdgcn_cvt_pk_fp8_f32(c, d, v, true);        // bytes 2,3
  return v;
}

// Prep:
//  blocks [0, 2048): LayerNorm + fp8-pack ALL 65536 feats rows into the 16 MB
//    table — grid-strided, two rows per wave per iteration. Table rows are
//    now LINEAR (byte c = channel c): the K=128 MFMA A-fragment for lane l is
//    the 32 contiguous bytes at 32*(l>>4) (+128 for the second K-step).
//  blocks [2048, 2560): lin_w -> fp8 x16 swizzle for the K=128 B-fragment,
//    n_xyz gather, n_offset.
__global__ void prep_kernel(const float* __restrict__ lin_w,
                            const float* __restrict__ xyz,
                            const float* __restrict__ feats,
                            const float* __restrict__ norm_w,
                            const float* __restrict__ norm_b,
                            const int*   __restrict__ samp_idx,
                            const int*   __restrict__ offset,
                            unsigned char* __restrict__ lw8,
                            unsigned char* __restrict__ tab,
                            float*  __restrict__ out) {
  int bx = blockIdx.x;
  if (bx < LN_BLOCKS) {
    const int lane = threadIdx.x & 63;
    const int gw   = (bx << 2) + (threadIdx.x >> 6);  // global wave 0..8191
    const float4 nw = ((const float4*)norm_w)[lane];
    const float4 nb = ((const float4*)norm_b)[lane];
    const float4* f4 = (const float4*)feats;
    const int wo = lane << 2;                         // LINEAR row layout
#pragma unroll
    for (int i = 0; i < 4; ++i) {
      const int ra = (i << 14) + (gw << 1);           // rows ra, ra+1
      float4 ga = f4[(size_t)ra * 64 + lane];
      float4 gb = f4[(size_t)(ra + 1) * 64 + lane];
      int pka = ln_pack(ga, nw, nb);                  // independent chains —
      int pkb = ln_pack(gb, nw, nb);                  // scheduler interleaves
      *(int*)(tab + ((size_t)ra << 8) + wo)       = pka;
      *(int*)(tab + ((size_t)(ra + 1) << 8) + wo) = pkb;
    }
    return;
  }
  int tid = (bx - LN_BLOCKS) * 256 + threadIdx.x;
  if (tid < COUT_C * CIN_C) {
    int o = tid >> 8;          // 0..511  (cout)
    int c = tid & 255;         // 0..255  (cin)
    // K=128 B-fragment: wave w = o>>5 owns cols [w*32,+32) as 2 groups of 16
    // (g = (o>>4)&1). MFMA(ks = c>>7) lane l = ((c>>5)&3)*16 + (o&15) supplies
    // col (o&15), k-byte b = c&31. Lane's 32 B contiguous for coalesced loads:
    // pos = w*8192 + g*4096 + ks*2048 + lane*32 + b
    int lanei = (((c >> 5) & 3) << 4) | (o & 15);
    int pos = ((o >> 5) << 13) | (((o >> 4) & 1) << 12) | ((c >> 7) << 11)
            | (lanei << 5) | (c & 31);
    int pk = __builtin_amdgcn_cvt_pk_fp8_f32(lin_w[tid] * B_SCALE, 0.0f, 0, false);
    lw8[pos] = (unsigned char)(pk & 0xFF);
  }
  if (tid < OUT_XYZ_ELEMS) {
    int p = tid / 3;
    int c = tid - p * 3;
    out[tid] = xyz[(size_t)samp_idx[p] * 3 + c];
  }
  if (tid == 0) out[OUT_NOFF_IDX] = (float)(offset[0] / 4 + 1);
}

// One 256 B table row -> LDS via direct DMA (4 B/lane, wave-uniform LDS base).
// src = tabL + preshifted row byte offset (Kidx holds idx<<8). Linear rows:
// LDS row bytes = channel order.
__device__ __forceinline__ void load_row(const unsigned char* __restrict__ src,
                                         unsigned char* ldsrow) {
  __builtin_amdgcn_global_load_lds(
      (const __attribute__((address_space(1))) unsigned int*)src,
      (__attribute__((address_space(3))) unsigned int*)ldsrow,
      4, 0, 0);
}

// 16-row maxpool reduce on the VALU pipe via permlane-swap builtins
// (R9-verified bit-exact vs shfl_xor). Robust to swap convention: both inputs
// equal -> outputs partition {v[l], v[l^16]}, so fmax of both is correct.
__device__ __forceinline__ float pool16(f32x4 a) {
  float v = fmaxf(fmaxf(a[0], a[1]), fmaxf(a[2], a[3]));
  uint2v r = __builtin_amdgcn_permlane16_swap(__float_as_uint(v), __float_as_uint(v), false, false);
  v = fmaxf(__uint_as_float(r.x), __uint_as_float(r.y));
  uint2v s = __builtin_amdgcn_permlane32_swap(__float_as_uint(v), __float_as_uint(v), false, false);
  return fmaxf(__uint_as_float(s.x), __uint_as_float(s.y));
}

// GEMM one point's 16x256 fp8 A-tile against the wave's 32-col B registers
// using the MX-scaled K=128 MFMA with identity scales (2x the fp8 rate), then
// maxpool over the 16 rows. rowbase = Ab + (lane&15)*AROW_B + (lane>>4)*32:
// lane supplies A row (lane&15), k-bytes 32*(lane>>4) (+128 for ks=1).
// C/D layout is shape-determined (== 16x16x32): col = lane&15,
// row = quad*4 + reg -> pool16 + store paths unchanged from R9.
__device__ __forceinline__ void gemm_pool(const unsigned char* rowbase,
                                          const i32x8 Breg[2][2],
                                          float& v0, float& v1) {
  i32x8 ak0 = *(const i32x8*)(rowbase);        // ks=0: channels [k32, k32+32)
  i32x8 ak1 = *(const i32x8*)(rowbase + 128);  // ks=1: + 128
  f32x4 a0 = {0.f, 0.f, 0.f, 0.f}, a1 = {0.f, 0.f, 0.f, 0.f};
  a0 = __builtin_amdgcn_mfma_scale_f32_16x16x128_f8f6f4(
         ak0, Breg[0][0], a0, 0, 0, 0, SCL_ONE, 0, SCL_ONE);
  a1 = __builtin_amdgcn_mfma_scale_f32_16x16x128_f8f6f4(
         ak0, Breg[1][0], a1, 0, 0, 0, SCL_ONE, 0, SCL_ONE);
  a0 = __builtin_amdgcn_mfma_scale_f32_16x16x128_f8f6f4(
         ak1, Breg[0][1], a0, 0, 0, 0, SCL_ONE, 0, SCL_ONE);
  a1 = __builtin_amdgcn_mfma_scale_f32_16x16x128_f8f6f4(
         ak1, Breg[1][1], a1, 0, 0, 0, SCL_ONE, 0, SCL_ONE);
  v0 = pool16(a0);
  v1 = pool16(a1);
}

// Fused main — R6/R9 structure (vmcnt pacing, barriers, grid identical):
// 1024 threads = 16 waves, 2 points/iter, 4-deep LDS rotation, counted-vmcnt
// 3/2/1, one raw barrier per iteration, runtime min() tail, NBLK=513.
// Only the GEMM core changed: 4 K=128 scaled MFMAs per point (was 16 K=32).
__global__ __launch_bounds__(1024, 8)
void td_main(const unsigned char* __restrict__ tab,
             const unsigned char* __restrict__ lw8,
             const int*    __restrict__ knn,
             float* __restrict__ out) {
  __shared__ __align__(16) unsigned char A8[4][32][AROW_B]; // 34816 B
  __shared__ int Kidx[PPB * K_NB];                          // 2048 B

  const int tid  = threadIdx.x;
  const int lane = tid & 63;
  const int w    = tid >> 6;        // wave = neighbor row AND 32-col chunk
  const int quad = lane >> 4;
  const int lcol = lane & 15;

  const int pstart = blockIdx.x * PPB;
  const int npts   = min(pstart + PPB, M_PTS) - pstart;
  if (npts <= 0) return;

  // Stage this block's knn indices, PRE-SHIFTED to row byte offsets (idx*256)
  for (int i = tid; i < npts * K_NB; i += 1024)
    Kidx[i] = knn[pstart * K_NB + i] << 8;

  // Persistent fp8 B chunk: Breg[g][ks], 32 VGPRs, 32 B/lane contiguous loads
  i32x8 Breg[2][2];
  {
    const unsigned char* base = lw8 + (w << 13) + lane * 32;
#pragma unroll
    for (int g = 0; g < 2; ++g)
#pragma unroll
      for (int ks = 0; ks < 2; ++ks) {
        Breg[g][ks] = *(const i32x8*)(base + (g << 12) + (ks << 11));
        asm volatile("" : "+v"(Breg[g][ks]));   // opaque: cannot be re-sunk
      }
  }

  const unsigned char* tabL = tab + (lane << 2);  // hoisted per-lane base

  __syncthreads();                  // Kidx visible (full sync, once)

  // Preload pair 0 into buffer 0
  load_row(tabL + (unsigned)Kidx[w],                           &A8[0][w][0]);
  load_row(tabL + (unsigned)Kidx[min(1, npts - 1) * K_NB + w], &A8[0][16 + w][0]);

  const int nit = (npts + 1) >> 1;
  for (int it = 0; it < nit; ++it) {
    const int pa = 2 * it, pb = 2 * it + 1;

    // Prefetch pair it+1 into buffer (it+1)&3 (crosses the barrier un-drained)
    if (it + 1 < nit) {
      int qa = min(pa + 2, npts - 1), qb = min(pa + 3, npts - 1);
      int b = (it + 1) & 3;
      load_row(tabL + (unsigned)Kidx[qa * K_NB + w], &A8[b][w][0]);
      load_row(tabL + (unsigned)Kidx[qb * K_NB + w], &A8[b][16 + w][0]);
    }

    // Counted vmcnt — EXACT R6/R9 pacing (steady 3, first 2, last 1).
    if (it == 0) {
      if (nit > 1) asm volatile("s_waitcnt vmcnt(2)" ::: "memory");
      else         asm volatile("s_waitcnt vmcnt(0)" ::: "memory");
    } else if (it + 1 < nit) {
      asm volatile("s_waitcnt vmcnt(3)" ::: "memory");
    } else {
      asm volatile("s_waitcnt vmcnt(1)" ::: "memory");
    }
    __builtin_amdgcn_s_barrier();   // all 32 rows of buffer it&3 landed

    const unsigned char* Ab = &A8[it & 3][0][0];
    const unsigned char* rowb = Ab + lcol * AROW_B + quad * 32;

    // GEMM + maxpool, point a then point b (store paths R9-exact)
    float v0, v1;
    gemm_pool(rowb, Breg, v0, v1);
    float* outa = out + OUT_FEAT_OFF + (size_t)(pstart + pa) * COUT_C + w * 32;
    if (quad < 2) outa[quad * 16 + lcol] = (quad ? v1 : v0) * B_INV;

    gemm_pool(rowb + 16 * AROW_B, Breg, v0, v1);
    if (pb < npts) {
      float* outb = out + OUT_FEAT_OFF + (size_t)(pstart + pb) * COUT_C + w * 32;
      if (quad < 2) outb[quad * 16 + lcol] = (quad ? v1 : v0) * B_INV;
    }
    // A[it&1..] reuse at it+4 is ordered by the intervening barriers.
  }
}

extern "C" void kernel_launch(void* const* d_in, const int* in_sizes, int n_in,
                              void* d_out, int out_size, void* d_ws, size_t ws_size,
                              hipStream_t stream) {
  const float* xyz      = (const float*)d_in[0];
  const float* feats    = (const float*)d_in[1];
  const float* norm_w   = (const float*)d_in[2];
  const float* norm_b   = (const float*)d_in[3];
  const float* lin_w    = (const float*)d_in[4];
  const int*   samp_idx = (const int*)d_in[5];
  const int*   knn      = (const int*)d_in[6];
  const int*   offset   = (const int*)d_in[7];
  float* out = (float*)d_out;
  unsigned char* lw8 = (unsigned char*)d_ws;               // 128 KB fp8 weights
  unsigned char* tab = (unsigned char*)d_ws + (1 << 17);   // 16 MB normed-fp8 feats

  prep_kernel<<<LN_BLOCKS + PREP_BLOCKS, 256, 0, stream>>>(
      lin_w, xyz, feats, norm_w, norm_b, samp_idx, offset, lw8, tab, out);

  td_main<<<NBLK, 1024, 0, stream>>>(tab, lw8, knn, out);
}